// Round 4
// baseline (999.157 us; speedup 1.0000x reference)
//
#include <hip/hip_runtime.h>
#include <hip/hip_fp16.h>

// GIN_MLP: 2x GIN conv (N=100000, E=1.6M, H=128) + per-batch context MLP (B=4096).
// Device-built dst-CSR (rank-based atomic-free scatter, 8-aligned padded rows)
// -> fused aggregate+GEMM -> tiled final MLP.
// R15: R13/R14 evidence shows conv gather is ADDRESS/VMEM-INSTRUCTION-rate
// bound (~48 lane-addr/edge = ~153us model, matches 158/146 measured; edge
// rate invariant to f32->fp16 line halving). Cut addresses 3x:
//  - fp16 rows 256B = 16 lanes x 16B -> one 64-lane dwordx4 gather covers
//    4 edges (was 2): 8 -> 4 gather insts per 16 edges.
//  - descriptors via SCALAR loads (readfirstlane + uniform s_load_dwordx16):
//    0 vector addresses (was 4 insts/16 edges). Weights selected from SGPR
//    by static cndmask tree.
//  - sub-batch (8 edges) = whole wave on ONE wave-uniform dst row: uniform
//    flush/walk/branches, natural LDS accumulator layout (permute pass gone).

#define CONV_NPB 32
#define FIN_EPB 8

struct __align__(8)  h4 { __half2 a, b; };
struct __align__(16) h8 { __half2 a, b, c, d; };

__device__ __forceinline__ float4 h4f(h4 u) {
  return make_float4(__low2float(u.a), __high2float(u.a),
                     __low2float(u.b), __high2float(u.b));
}
__device__ __forceinline__ h4 f4h(float4 v) {
  h4 u; u.a = __floats2half2_rn(v.x, v.y); u.b = __floats2half2_rn(v.z, v.w);
  return u;
}
__device__ __forceinline__ void fma8(float (&ac)[8], h8 u, float w) {
  ac[0] += w * __low2float(u.a);  ac[1] += w * __high2float(u.a);
  ac[2] += w * __low2float(u.b);  ac[3] += w * __high2float(u.b);
  ac[4] += w * __low2float(u.c);  ac[5] += w * __high2float(u.c);
  ac[6] += w * __low2float(u.d);  ac[7] += w * __high2float(u.d);
}

// select among 4 by lane-group (compiles to cndmask tree; all indices static)
#define SEL4(g, a, b, c, d) ((g) < 2 ? ((g) == 0 ? (a) : (b)) : ((g) == 2 ? (c) : (d)))

// init: weight transposes + cnt zeroing + fp16 cast of ndata (8 elems/thread)
__global__ void init_kernel(const float* __restrict__ W1, const float* __restrict__ W2,
                            const float* __restrict__ Wc1, const float* __restrict__ Wc2,
                            const float* __restrict__ ndata, __half* __restrict__ xh0,
                            float* __restrict__ Wt1, float* __restrict__ Wt2,
                            float* __restrict__ Wc1t, float* __restrict__ Wc2t,
                            int* __restrict__ cnt, int n) {
  int i = blockIdx.x * blockDim.x + threadIdx.x;
  if (i < n) cnt[i] = 0;
  const int cbase = i * 8;
  if (cbase < n * 128) {
    const float4 v0 = *(const float4*)&ndata[cbase];
    const float4 v1 = *(const float4*)&ndata[cbase + 4];
    h8 u;
    u.a = __floats2half2_rn(v0.x, v0.y);
    u.b = __floats2half2_rn(v0.z, v0.w);
    u.c = __floats2half2_rn(v1.x, v1.y);
    u.d = __floats2half2_rn(v1.z, v1.w);
    *(h8*)&xh0[cbase] = u;
  }
  if (i < 16384) {
    int f = i >> 7, k = i & 127;
    Wt1[k * 128 + f] = W1[i];
  } else if (i < 32768) {
    int j = i - 16384; int f = j >> 7, k = j & 127;
    Wt2[k * 128 + f] = W2[j];
  } else if (i < 81920) {
    int j = i - 32768; int f = j / 384, k = j % 384;
    Wc1t[k * 128 + f] = Wc1[j];
  } else if (i < 90112) {
    int j = i - 81920; int f = j >> 7, k = j & 127;
    Wc2t[k * 64 + f] = Wc2[j];
  }
}

// per-dst degree + per-edge arrival rank; 4 edges/thread
__global__ void hist_kernel(const int* __restrict__ dst, int* __restrict__ cnt,
                            int* __restrict__ rank, int E) {
  int e = (blockIdx.x * blockDim.x + threadIdx.x) * 4;
  if (e + 3 < E) {
    const int4 d = *(const int4*)&dst[e];
    int4 r;
    r.x = atomicAdd(&cnt[d.x], 1);
    r.y = atomicAdd(&cnt[d.y], 1);
    r.z = atomicAdd(&cnt[d.z], 1);
    r.w = atomicAdd(&cnt[d.w], 1);
    *(int4*)&rank[e] = r;
  } else {
    for (; e < E; ++e) rank[e] = atomicAdd(&cnt[dst[e]], 1);
  }
}

// per-2048-chunk exclusive scan of PADDED counts (ceil(cnt/8)*8); bsum[b] = chunk total
__global__ void scan1_kernel(const int* __restrict__ cnt, int* __restrict__ prow,
                             int* __restrict__ bsum, int n) {
  __shared__ int smem[256];
  const int t = threadIdx.x;
  const int base = blockIdx.x * 2048 + t * 8;
  int v[8];
  int s = 0;
#pragma unroll
  for (int j = 0; j < 8; ++j) {
    int idx = base + j;
    v[j] = (idx < n) ? ((cnt[idx] + 7) & ~7) : 0;
    s += v[j];
  }
  smem[t] = s;
  __syncthreads();
  for (int off = 1; off < 256; off <<= 1) {
    int add = (t >= off) ? smem[t - off] : 0;
    __syncthreads();
    smem[t] += add;
    __syncthreads();
  }
  int run = smem[t] - s;
  if (t == 255) bsum[blockIdx.x] = smem[255];
#pragma unroll
  for (int j = 0; j < 8; ++j) {
    int idx = base + j;
    if (idx < n) prow[idx] = run;
    run += v[j];
  }
}

// 64-lane shuffle scan (nchunk=49 fits); appends grand total at bsum[nb]
__global__ void scan2_kernel(int* __restrict__ bsum, int nb) {
  const int t = threadIdx.x;
  if (nb <= 64) {
    const int orig = (t < nb) ? bsum[t] : 0;
    int v = orig;
#pragma unroll
    for (int off = 1; off < 64; off <<= 1) {
      int u = __shfl_up(v, off);
      if (t >= off) v += u;
    }
    if (t == nb - 1) bsum[nb] = v;
    if (t < nb) bsum[t] = v - orig;
  } else if (t == 0) {
    int run = 0;
    for (int i = 0; i < nb; ++i) { int v = bsum[i]; bsum[i] = run; run += v; }
    bsum[nb] = run;
  }
}

// atomic-free scatter into padded CSR, 4 edges/thread; threads i<n also zero
// their node's pad slots (real + pad slots exactly partition the padded CSR)
__global__ void scatter_kernel(const int* __restrict__ src, const int* __restrict__ dst,
                               const float* __restrict__ w, const int* __restrict__ prow,
                               const int* __restrict__ bsum, const int* __restrict__ rank,
                               const int* __restrict__ cnt,
                               int2* __restrict__ epack, int E, int n) {
  const int i = blockIdx.x * blockDim.x + threadIdx.x;
  int e = i * 4;
  if (e + 3 < E) {
    const int4 d = *(const int4*)&dst[e];
    const int4 s = *(const int4*)&src[e];
    const float4 wv = *(const float4*)&w[e];
    const int4 r = *(const int4*)&rank[e];
    epack[prow[d.x] + bsum[d.x >> 11] + r.x] = make_int2(s.x, __float_as_int(wv.x));
    epack[prow[d.y] + bsum[d.y >> 11] + r.y] = make_int2(s.y, __float_as_int(wv.y));
    epack[prow[d.z] + bsum[d.z >> 11] + r.z] = make_int2(s.z, __float_as_int(wv.z));
    epack[prow[d.w] + bsum[d.w >> 11] + r.w] = make_int2(s.w, __float_as_int(wv.w));
  } else {
    for (; e < E; ++e) {
      const int d = dst[e];
      epack[prow[d] + bsum[d >> 11] + rank[e]] = make_int2(src[e], __float_as_int(w[e]));
    }
  }
  if (i < n) {
    const int c = cnt[i];
    const int start = prow[i] + bsum[i >> 11] + c;
    const int pc = ((c + 7) & ~7) - c;
    for (int j = 0; j < pc; ++j) epack[start + j] = make_int2(0, 0);
  }
}

// R15 conv. Stage 1: per wave, contiguous range of 8-edge sub-batches (each
// sub-batch lies in exactly ONE dst row, wave-uniform). Per sub-batch:
// 2 x 64-lane dwordx4 gathers (4 fp16 rows each; lane = grp(row) x fl(8 feats))
// + scalar s_load desc prefetch. acc[8]/lane accumulates across sub-batches of
// a row; uniform flush -> 8 LDS atomics into NATURAL layout xm[r*128+f].
// Stage 2: in-place (1+eps)x + agg/deg. Stage 3: GEMM (f32), unchanged.
__launch_bounds__(256, 8)
__global__ void conv_kernel(const float* __restrict__ xin, const __half* __restrict__ xinh,
                            float* __restrict__ xout, __half* __restrict__ xouth,
                            const int* __restrict__ prow, const int* __restrict__ bsum,
                            const int* __restrict__ cnt,
                            const int2* __restrict__ epack,
                            const float* __restrict__ Wt,
                            const float* __restrict__ bias, const float* __restrict__ eps,
                            int epsidx, int dorelu, int zerorow0, int writef32,
                            int n, int nchunk) {
  __shared__ float xm[CONV_NPB * 128];
  __shared__ int rp_s[CONV_NPB + 1];
  const int t = threadIdx.x;
  const int nb = blockIdx.x * CONV_NPB;
  const float epsv = 1.0f + eps[epsidx];

#pragma unroll
  for (int i = 0; i < 4; ++i)
    *(float4*)&xm[(t + i * 256) * 4] = make_float4(0.f, 0.f, 0.f, 0.f);
  if (t <= CONV_NPB) {
    const int node = nb + t;
    rp_s[t] = (node >= n) ? bsum[nchunk] : (prow[node] + bsum[node >> 11]);
  }
  __syncthreads();

  // ---- stage 1 ----
  {
    const int lane = t & 63;
    const int wv = t >> 6;
    const int grp = lane >> 4;        // which row within a gather inst (0..3)
    const int fl = lane & 15;         // feature group: features 8fl..8fl+7
    const int e0 = rp_s[0], eT = rp_s[CONV_NPB];
    const int sbT = (eT - e0) >> 3;   // sub-batches in block
    const int csb = (sbT + 3) >> 2;
    const int sw0 = wv * csb;
    const int send = min(sw0 + csb, sbT);
    if (sw0 < send) {
      const int* epi = (const int*)epack;
      const int sbase = e0 >> 3;      // global sub-batch index base
      float acc[8];
#pragma unroll
      for (int c = 0; c < 8; ++c) acc[c] = 0.f;
      int dvA[16], dvB[16];
      h8 gA0, gA1, gB0, gB1;
      float wA0, wA1, wB0, wB1;

#define LOADDESC(dv, si) do {                                            \
        const int _db = __builtin_amdgcn_readfirstlane(sbase + (si)) << 4; \
        _Pragma("unroll")                                                \
        for (int _k = 0; _k < 16; ++_k) (dv)[_k] = epi[_db + _k];        \
      } while (0)

#define ISSUEG(dv, g0, g1, ww0, ww1) do {                                \
        const int _s0 = SEL4(grp, (dv)[0], (dv)[2], (dv)[4], (dv)[6]);   \
        const int _s1 = SEL4(grp, (dv)[8], (dv)[10], (dv)[12], (dv)[14]);\
        (ww0) = __int_as_float(SEL4(grp, (dv)[1], (dv)[3], (dv)[5], (dv)[7]));   \
        (ww1) = __int_as_float(SEL4(grp, (dv)[9], (dv)[11], (dv)[13], (dv)[15]));\
        (g0) = *(const h8*)&xinh[(size_t)_s0 * 128 + fl * 8];            \
        (g1) = *(const h8*)&xinh[(size_t)_s1 * 128 + fl * 8];            \
      } while (0)

#define FLUSHACC(rr) do {                                                \
        float* _bp = &xm[(rr) * 128 + fl * 8];                           \
        _Pragma("unroll")                                                \
        for (int _c = 0; _c < 8; ++_c) {                                 \
          atomicAdd(_bp + _c, acc[_c]); acc[_c] = 0.f;                   \
        }                                                                \
      } while (0)

      // prologue
      LOADDESC(dvA, sw0);
      ISSUEG(dvA, gA0, gA1, wA0, wA1);
      if (sw0 + 1 < send) LOADDESC(dvB, sw0 + 1);
      int r = 0;
      for (int i = sw0; i < send; i += 2) {
        const bool hasB = (i + 1 < send);
        if (hasB) ISSUEG(dvB, gB0, gB1, wB0, wB1);
        if (i + 2 < send) LOADDESC(dvA, i + 2);
        {
          const int j = e0 + 8 * i;
          int rn = r;
          while (rp_s[rn + 1] <= j) ++rn;
          if (rn != r) { FLUSHACC(r); r = rn; }
        }
        fma8(acc, gA0, wA0);
        fma8(acc, gA1, wA1);
        if (hasB) {
          if (i + 2 < send) ISSUEG(dvA, gA0, gA1, wA0, wA1);
          if (i + 3 < send) LOADDESC(dvB, i + 3);
          {
            const int j = e0 + 8 * (i + 1);
            int rn = r;
            while (rp_s[rn + 1] <= j) ++rn;
            if (rn != r) { FLUSHACC(r); r = rn; }
          }
          fma8(acc, gB0, wB0);
          fma8(acc, gB1, wB1);
        }
      }
      FLUSHACC(r);
#undef LOADDESC
#undef ISSUEG
#undef FLUSHACC
    }
  }
  __syncthreads();

  // ---- stage 2: in-place finalize (1+eps)*x + agg/deg (natural layout) ----
  {
#pragma unroll
    for (int q = 0; q < 4; ++q) {
      const int task = t + q * 256;
      const int r = task >> 5;
      const int fg = task & 31;
      const int f0 = fg * 4;
      const int node = nb + r;
      float4 v = make_float4(0.f, 0.f, 0.f, 0.f);
      if (node < n) {
        const int d = cnt[node];
        const float rdeg = 1.0f / (float)(d > 1 ? d : 1);
        const float4 xv = *(const float4*)&xin[(size_t)node * 128 + f0];
        const float4 m = *(const float4*)&xm[r * 128 + f0];
        v.x = epsv * xv.x + m.x * rdeg;
        v.y = epsv * xv.y + m.y * rdeg;
        v.z = epsv * xv.z + m.z * rdeg;
        v.w = epsv * xv.w + m.w * rdeg;
      }
      *(float4*)&xm[r * 128 + f0] = v;   // each (r,f0) owned by one thread
    }
  }
  __syncthreads();

  // ---- stage 3: GEMM, thread tile = 4 rows x 4 features ----
  {
    const int fg = t & 31;
    const int rg = t >> 5;
    const int f0 = fg * 4;
    const int r0 = rg * 4;
    float4 acc[4];
#pragma unroll
    for (int r = 0; r < 4; ++r) acc[r] = make_float4(0.f, 0.f, 0.f, 0.f);
    for (int k = 0; k < 128; k += 4) {
      const float4 w0 = *(const float4*)&Wt[(k + 0) * 128 + f0];
      const float4 w1 = *(const float4*)&Wt[(k + 1) * 128 + f0];
      const float4 w2 = *(const float4*)&Wt[(k + 2) * 128 + f0];
      const float4 w3 = *(const float4*)&Wt[(k + 3) * 128 + f0];
#pragma unroll
      for (int r = 0; r < 4; ++r) {
        const float4 xv = *(const float4*)&xm[(r0 + r) * 128 + k];
        acc[r].x += xv.x * w0.x + xv.y * w1.x + xv.z * w2.x + xv.w * w3.x;
        acc[r].y += xv.x * w0.y + xv.y * w1.y + xv.z * w2.y + xv.w * w3.y;
        acc[r].z += xv.x * w0.z + xv.y * w1.z + xv.z * w2.z + xv.w * w3.z;
        acc[r].w += xv.x * w0.w + xv.y * w1.w + xv.z * w2.w + xv.w * w3.w;
      }
    }
    const float4 bv = *(const float4*)&bias[f0];
#pragma unroll
    for (int r = 0; r < 4; ++r) {
      const int node = nb + r0 + r;
      if (node < n) {
        float4 v;
        v.x = acc[r].x + bv.x;
        v.y = acc[r].y + bv.y;
        v.z = acc[r].z + bv.z;
        v.w = acc[r].w + bv.w;
        if (dorelu) {
          v.x = fmaxf(v.x, 0.f); v.y = fmaxf(v.y, 0.f);
          v.z = fmaxf(v.z, 0.f); v.w = fmaxf(v.w, 0.f);
        }
        if (zerorow0 && node == 0) { v.x = 0.f; v.y = 0.f; v.z = 0.f; v.w = 0.f; }
        *(h4*)&xouth[(size_t)node * 128 + f0] = f4h(v);
        if (writef32) *(float4*)&xout[(size_t)node * 128 + f0] = v;
      }
    }
  }
}

// Final MLP: 8 elems per 256-thread block (512 blocks); x2 gathers in fp16.
__launch_bounds__(256, 4)
__global__ void final_kernel(const __half* __restrict__ x2h, const int* __restrict__ indices,
                             const float* __restrict__ Wc1t, const float* __restrict__ bc1,
                             const float* __restrict__ Wc2t, const float* __restrict__ bc2,
                             const float* __restrict__ Wc3, const float* __restrict__ bc3,
                             float* __restrict__ out) {
  __shared__ float ysm[FIN_EPB * 384];
  __shared__ float h1s[FIN_EPB * 128];
  __shared__ float h2s[FIN_EPB * 64];
  __shared__ int ind_s[FIN_EPB * 23];
  __shared__ float ccs[FIN_EPB];
  const int t = threadIdx.x;
  const int b0 = blockIdx.x * FIN_EPB;

  if (t < FIN_EPB * 23) ind_s[t] = indices[(size_t)b0 * 23 + t];
  __syncthreads();
  if (t < FIN_EPB) {
    int cc = 0;
#pragma unroll
    for (int j = 0; j < 20; ++j) cc += (ind_s[t * 23 + 3 + j] > 0) ? 1 : 0;
    ccs[t] = 1.0f / (float)(cc > 0 ? cc : 1);
  }
  __syncthreads();

  // ---- phase A ----
  {
#pragma unroll
    for (int q = 0; q < 2; ++q) {
      const int s = t + q * 256;
      const int e = s >> 6;
      const int hf = (s >> 5) & 1;
      const int fg = s & 31;
      const int idx = ind_s[e * 23 + hf];
      const h4 u = *(const h4*)&x2h[(size_t)idx * 128 + fg * 4];
      *(float4*)&ysm[e * 384 + hf * 128 + fg * 4] = h4f(u);
    }
    const int e = t >> 5;
    const int fg = t & 31;
    float4 acc = make_float4(0.f, 0.f, 0.f, 0.f);
#pragma unroll
    for (int j = 0; j < 20; ++j) {
      const int cj = ind_s[e * 23 + 3 + j];
      const h4 u = *(const h4*)&x2h[(size_t)cj * 128 + fg * 4];
      const float4 a = h4f(u);
      acc.x += a.x; acc.y += a.y; acc.z += a.z; acc.w += a.w;
    }
    const float sc = ccs[e];
    acc.x *= sc; acc.y *= sc; acc.z *= sc; acc.w *= sc;
    *(float4*)&ysm[e * 384 + 256 + fg * 4] = acc;
  }
  __syncthreads();

  // ---- phase B: layer 1 (384 -> 128), 4 elems per thread ----
  {
    const int f1 = t & 127;
    const int eh = t >> 7;
    float acc[4];
    const float b = bc1[f1];
#pragma unroll
    for (int i = 0; i < 4; ++i) acc[i] = b;
    for (int k = 0; k < 384; k += 4) {
      const float wv0 = Wc1t[(k + 0) * 128 + f1];
      const float wv1 = Wc1t[(k + 1) * 128 + f1];
      const float wv2 = Wc1t[(k + 2) * 128 + f1];
      const float wv3 = Wc1t[(k + 3) * 128 + f1];
#pragma unroll
      for (int i = 0; i < 4; ++i) {
        const float4 yv = *(const float4*)&ysm[(eh * 4 + i) * 384 + k];
        acc[i] += yv.x * wv0 + yv.y * wv1 + yv.z * wv2 + yv.w * wv3;
      }
    }
#pragma unroll
    for (int i = 0; i < 4; ++i)
      h1s[(eh * 4 + i) * 128 + f1] = fmaxf(acc[i], 0.f);
  }
  __syncthreads();

  // ---- phase C: layer 2 (128 -> 64), 2 elems per thread ----
  {
    const int f2 = t & 63;
    const int eg = t >> 6;
    float acc[2];
    const float b = bc2[f2];
#pragma unroll
    for (int i = 0; i < 2; ++i) acc[i] = b;
    for (int k = 0; k < 128; k += 4) {
      const float wv0 = Wc2t[(k + 0) * 64 + f2];
      const float wv1 = Wc2t[(k + 1) * 64 + f2];
      const float wv2 = Wc2t[(k + 2) * 64 + f2];
      const float wv3 = Wc2t[(k + 3) * 64 + f2];
#pragma unroll
      for (int i = 0; i < 2; ++i) {
        const float4 hv = *(const float4*)&h1s[(eg * 2 + i) * 128 + k];
        acc[i] += hv.x * wv0 + hv.y * wv1 + hv.z * wv2 + hv.w * wv3;
      }
    }
#pragma unroll
    for (int i = 0; i < 2; ++i)
      h2s[(eg * 2 + i) * 64 + f2] = fmaxf(acc[i], 0.f);
  }
  __syncthreads();

  // ---- phase D: layer 3 (64 -> 1), 32 lanes per element ----
  {
    const int e = t >> 5;
    const int l = t & 31;
    float p = h2s[e * 64 + l] * Wc3[l] + h2s[e * 64 + l + 32] * Wc3[l + 32];
#pragma unroll
    for (int o = 16; o > 0; o >>= 1) p += __shfl_down(p, o, 32);
    if (l == 0) out[b0 + e] = p + bc3[0];
  }
}

extern "C" void kernel_launch(void* const* d_in, const int* in_sizes, int n_in,
                              void* d_out, int out_size, void* d_ws, size_t ws_size,
                              hipStream_t stream) {
  const int* indices = (const int*)d_in[0];
  const int* src = (const int*)d_in[1];
  const int* dst = (const int*)d_in[2];
  const float* w = (const float*)d_in[3];
  const float* ndata = (const float*)d_in[4];
  const float* W1 = (const float*)d_in[5];
  const float* b1 = (const float*)d_in[6];
  const float* W2 = (const float*)d_in[7];
  const float* b2 = (const float*)d_in[8];
  const float* eps = (const float*)d_in[9];
  const float* Wc1 = (const float*)d_in[10];
  const float* bc1 = (const float*)d_in[11];
  const float* Wc2 = (const float*)d_in[12];
  const float* bc2 = (const float*)d_in[13];
  const float* Wc3 = (const float*)d_in[14];
  const float* bc3 = (const float*)d_in[15];
  float* out = (float*)d_out;

  const int E = in_sizes[1];
  const int N = in_sizes[4] / 128;
  const int B = in_sizes[0] / 23;

  char* ws = (char*)d_ws;
  size_t off = 0;
  auto alloc = [&](size_t bytes) -> char* {
    char* p = ws + off;
    off = (off + bytes + 255) & ~(size_t)255;
    return p;
  };
  const size_t Epad = (size_t)E + 8 * (size_t)N;   // worst-case padded edge count
  int* cnt = (int*)alloc((size_t)N * 4);
  int* prow = (int*)alloc((size_t)(N + 1) * 4);
  int* rank = (int*)alloc((size_t)E * 4);
  int* bsum = (int*)alloc(256 * 4);
  int2* epack = (int2*)alloc(Epad * 8);
  float* x1 = (float*)alloc((size_t)N * 128 * 4);          // f32 x1 (conv2 self term)
  __half* xh0 = (__half*)alloc((size_t)N * 128 * 2);       // fp16 ndata; reused as x2h
  __half* x1h = (__half*)alloc((size_t)N * 128 * 2);       // fp16 x1 (conv2 gathers)
  float* Wt1 = (float*)alloc(16384 * 4);
  float* Wt2 = (float*)alloc(16384 * 4);
  float* Wc1t = (float*)alloc(49152 * 4);
  float* Wc2t = (float*)alloc(8192 * 4);
  __half* x2h = xh0;   // xh0 dead after conv1; conv2 writes x2 (fp16) here

  const int ncast = (N * 128 + 7) / 8;                     // 1.6M cast threads
  int ninit = (N > 90112) ? N : 90112;
  if (ncast > ninit) ninit = ncast;
  init_kernel<<<(ninit + 255) / 256, 256, 0, stream>>>(W1, W2, Wc1, Wc2, ndata, xh0,
                                                       Wt1, Wt2, Wc1t, Wc2t, cnt, N);
  const int Eq = (E + 3) / 4;
  hist_kernel<<<(Eq + 255) / 256, 256, 0, stream>>>(dst, cnt, rank, E);
  const int nchunk = (N + 2047) / 2048;
  scan1_kernel<<<nchunk, 256, 0, stream>>>(cnt, prow, bsum, N);
  scan2_kernel<<<1, 64, 0, stream>>>(bsum, nchunk);
  const int nsc = (Eq > N) ? Eq : N;
  scatter_kernel<<<(nsc + 255) / 256, 256, 0, stream>>>(src, dst, w, prow, bsum, rank, cnt, epack, E, N);

  const int nconv = (N + CONV_NPB - 1) / CONV_NPB;
  // conv1: gathers fp16(ndata), self term f32 ndata; writes x1 (f32) + x1h (fp16)
  conv_kernel<<<nconv, 256, 0, stream>>>(ndata, xh0, x1, x1h, prow, bsum, cnt, epack,
                                         Wt1, b1, eps, 0, 1, 0, 1, N, nchunk);
  // conv2: gathers x1h, self term f32 x1; writes x2h (fp16 only, into xh0 buffer)
  conv_kernel<<<nconv, 256, 0, stream>>>(x1, x1h, nullptr, x2h, prow, bsum, cnt, epack,
                                         Wt2, b2, eps, 1, 0, 1, 0, N, nchunk);

  final_kernel<<<B / FIN_EPB, 256, 0, stream>>>(x2h, indices, Wc1t, bc1, Wc2t, bc2, Wc3, bc3, out);
}

// Round 5
// 641.030 us; speedup vs baseline: 1.5587x; 1.5587x over previous
//
#include <hip/hip_runtime.h>
#include <hip/hip_fp16.h>

// GIN_MLP: 2x GIN conv (N=100000, E=1.6M, H=128) + per-batch context MLP (B=4096).
// Device-built dst-CSR (rank-based atomic-free scatter, 8-aligned padded rows)
// -> fused aggregate+GEMM -> tiled final MLP.
// R16: conv gather is per-lane-ADDRESS-rate bound (~1 lane-addr/cy/CU: 48/edge
// model = 125us, matches R14's 146; edge rate invariant to f32/fp16 and
// line-count). R15's scalar-descriptor attempt spilled to scratch (WRITE 675MB).
// R16 keeps R14's skeleton exactly (laneset chunks, broadcast int4 descriptor
// prefetch) and changes ONLY gather geometry: 16B/lane h8 -> 16 lanes/row,
// one inst gathers 4 edges (was 2). Lane-addrs 48 -> 32/edge. Flush becomes
// natural-layout LDS atomics (permute pass deleted; stage 2 from R15).

#define CONV_NPB 32
#define FIN_EPB 8

struct __align__(8)  h4 { __half2 a, b; };
struct __align__(16) h8 { __half2 a, b, c, d; };

__device__ __forceinline__ float4 h4f(h4 u) {
  return make_float4(__low2float(u.a), __high2float(u.a),
                     __low2float(u.b), __high2float(u.b));
}
__device__ __forceinline__ h4 f4h(float4 v) {
  h4 u; u.a = __floats2half2_rn(v.x, v.y); u.b = __floats2half2_rn(v.z, v.w);
  return u;
}
__device__ __forceinline__ void fma8(float (&ac)[8], h8 u, float w) {
  ac[0] += w * __low2float(u.a);  ac[1] += w * __high2float(u.a);
  ac[2] += w * __low2float(u.b);  ac[3] += w * __high2float(u.b);
  ac[4] += w * __low2float(u.c);  ac[5] += w * __high2float(u.c);
  ac[6] += w * __low2float(u.d);  ac[7] += w * __high2float(u.d);
}

// init: weight transposes + cnt zeroing + fp16 cast of ndata (8 elems/thread)
__global__ void init_kernel(const float* __restrict__ W1, const float* __restrict__ W2,
                            const float* __restrict__ Wc1, const float* __restrict__ Wc2,
                            const float* __restrict__ ndata, __half* __restrict__ xh0,
                            float* __restrict__ Wt1, float* __restrict__ Wt2,
                            float* __restrict__ Wc1t, float* __restrict__ Wc2t,
                            int* __restrict__ cnt, int n) {
  int i = blockIdx.x * blockDim.x + threadIdx.x;
  if (i < n) cnt[i] = 0;
  const int cbase = i * 8;
  if (cbase < n * 128) {
    const float4 v0 = *(const float4*)&ndata[cbase];
    const float4 v1 = *(const float4*)&ndata[cbase + 4];
    h8 u;
    u.a = __floats2half2_rn(v0.x, v0.y);
    u.b = __floats2half2_rn(v0.z, v0.w);
    u.c = __floats2half2_rn(v1.x, v1.y);
    u.d = __floats2half2_rn(v1.z, v1.w);
    *(h8*)&xh0[cbase] = u;
  }
  if (i < 16384) {
    int f = i >> 7, k = i & 127;
    Wt1[k * 128 + f] = W1[i];
  } else if (i < 32768) {
    int j = i - 16384; int f = j >> 7, k = j & 127;
    Wt2[k * 128 + f] = W2[j];
  } else if (i < 81920) {
    int j = i - 32768; int f = j / 384, k = j % 384;
    Wc1t[k * 128 + f] = Wc1[j];
  } else if (i < 90112) {
    int j = i - 81920; int f = j >> 7, k = j & 127;
    Wc2t[k * 64 + f] = Wc2[j];
  }
}

// per-dst degree + per-edge arrival rank; 4 edges/thread
__global__ void hist_kernel(const int* __restrict__ dst, int* __restrict__ cnt,
                            int* __restrict__ rank, int E) {
  int e = (blockIdx.x * blockDim.x + threadIdx.x) * 4;
  if (e + 3 < E) {
    const int4 d = *(const int4*)&dst[e];
    int4 r;
    r.x = atomicAdd(&cnt[d.x], 1);
    r.y = atomicAdd(&cnt[d.y], 1);
    r.z = atomicAdd(&cnt[d.z], 1);
    r.w = atomicAdd(&cnt[d.w], 1);
    *(int4*)&rank[e] = r;
  } else {
    for (; e < E; ++e) rank[e] = atomicAdd(&cnt[dst[e]], 1);
  }
}

// per-2048-chunk exclusive scan of PADDED counts (ceil(cnt/8)*8); bsum[b] = chunk total
__global__ void scan1_kernel(const int* __restrict__ cnt, int* __restrict__ prow,
                             int* __restrict__ bsum, int n) {
  __shared__ int smem[256];
  const int t = threadIdx.x;
  const int base = blockIdx.x * 2048 + t * 8;
  int v[8];
  int s = 0;
#pragma unroll
  for (int j = 0; j < 8; ++j) {
    int idx = base + j;
    v[j] = (idx < n) ? ((cnt[idx] + 7) & ~7) : 0;
    s += v[j];
  }
  smem[t] = s;
  __syncthreads();
  for (int off = 1; off < 256; off <<= 1) {
    int add = (t >= off) ? smem[t - off] : 0;
    __syncthreads();
    smem[t] += add;
    __syncthreads();
  }
  int run = smem[t] - s;
  if (t == 255) bsum[blockIdx.x] = smem[255];
#pragma unroll
  for (int j = 0; j < 8; ++j) {
    int idx = base + j;
    if (idx < n) prow[idx] = run;
    run += v[j];
  }
}

// 64-lane shuffle scan (nchunk=49 fits); appends grand total at bsum[nb]
__global__ void scan2_kernel(int* __restrict__ bsum, int nb) {
  const int t = threadIdx.x;
  if (nb <= 64) {
    const int orig = (t < nb) ? bsum[t] : 0;
    int v = orig;
#pragma unroll
    for (int off = 1; off < 64; off <<= 1) {
      int u = __shfl_up(v, off);
      if (t >= off) v += u;
    }
    if (t == nb - 1) bsum[nb] = v;
    if (t < nb) bsum[t] = v - orig;
  } else if (t == 0) {
    int run = 0;
    for (int i = 0; i < nb; ++i) { int v = bsum[i]; bsum[i] = run; run += v; }
    bsum[nb] = run;
  }
}

// atomic-free scatter into padded CSR, 4 edges/thread; threads i<n also zero
// their node's pad slots (real + pad slots exactly partition the padded CSR)
__global__ void scatter_kernel(const int* __restrict__ src, const int* __restrict__ dst,
                               const float* __restrict__ w, const int* __restrict__ prow,
                               const int* __restrict__ bsum, const int* __restrict__ rank,
                               const int* __restrict__ cnt,
                               int2* __restrict__ epack, int E, int n) {
  const int i = blockIdx.x * blockDim.x + threadIdx.x;
  int e = i * 4;
  if (e + 3 < E) {
    const int4 d = *(const int4*)&dst[e];
    const int4 s = *(const int4*)&src[e];
    const float4 wv = *(const float4*)&w[e];
    const int4 r = *(const int4*)&rank[e];
    epack[prow[d.x] + bsum[d.x >> 11] + r.x] = make_int2(s.x, __float_as_int(wv.x));
    epack[prow[d.y] + bsum[d.y >> 11] + r.y] = make_int2(s.y, __float_as_int(wv.y));
    epack[prow[d.z] + bsum[d.z >> 11] + r.z] = make_int2(s.z, __float_as_int(wv.z));
    epack[prow[d.w] + bsum[d.w >> 11] + r.w] = make_int2(s.w, __float_as_int(wv.w));
  } else {
    for (; e < E; ++e) {
      const int d = dst[e];
      epack[prow[d] + bsum[d >> 11] + rank[e]] = make_int2(src[e], __float_as_int(w[e]));
    }
  }
  if (i < n) {
    const int c = cnt[i];
    const int start = prow[i] + bsum[i >> 11] + c;
    const int pc = ((c + 7) & ~7) - c;
    for (int j = 0; j < pc; ++j) epack[start + j] = make_int2(0, 0);
  }
}

// Stage 1 (R16): block's 32 rows = contiguous 8-aligned padded edge range,
// split into 8 laneset chunks (edges, multiple of 8). Every 8-edge batch lies
// in ONE row (padding invariant). Per batch: 4 broadcast int4 descriptor loads
// (prefetched, as R14) + 4 x 64-lane h8 gathers (16 lanes/row, grp=lane>>4
// picks edge 2i+grp of q_i via cndmask) + 32 FMA. acc[8]/lane flushes to LDS
// NATURAL layout (xm[r*128 + fl*8 + c], 8 atomics, 2-way grp contention) only
// at row transitions. Stage 2: in-place (1+eps)x + agg/deg. Stage 3: GEMM f32.
__launch_bounds__(256, 8)
__global__ void conv_kernel(const float* __restrict__ xin, const __half* __restrict__ xinh,
                            float* __restrict__ xout, __half* __restrict__ xouth,
                            const int* __restrict__ prow, const int* __restrict__ bsum,
                            const int* __restrict__ cnt,
                            const int2* __restrict__ epack,
                            const float* __restrict__ Wt,
                            const float* __restrict__ bias, const float* __restrict__ eps,
                            int epsidx, int dorelu, int zerorow0, int writef32,
                            int n, int nchunk) {
  __shared__ float xm[CONV_NPB * 128];
  __shared__ int rp_s[CONV_NPB + 1];
  const int t = threadIdx.x;
  const int nb = blockIdx.x * CONV_NPB;
  const float epsv = 1.0f + eps[epsidx];

#pragma unroll
  for (int i = 0; i < 4; ++i)
    *(float4*)&xm[(t + i * 256) * 4] = make_float4(0.f, 0.f, 0.f, 0.f);
  if (t <= CONV_NPB) {
    const int node = nb + t;
    rp_s[t] = (node >= n) ? bsum[nchunk] : (prow[node] + bsum[node >> 11]);
  }
  __syncthreads();

  // ---- stage 1: h8 laneset gather with broadcast descriptor prefetch ----
  {
    const int L = t >> 5;             // laneset 0..7
    const int lane = t & 31;
    const int grp = lane >> 4;        // edge parity within descriptor pair
    const int fl = lane & 15;         // feature block: 8*fl .. 8*fl+7
    const int e0 = rp_s[0], eT = rp_s[CONV_NPB];
    const int nbat = (eT - e0) >> 3;
    const int chunk = (((nbat + 7) >> 3)) << 3;   // edges per laneset, x8
    const int jb = e0 + L * chunk;
    const int je = min(jb + chunk, eT);
    if (jb < je) {
      const int4* ep4 = (const int4*)epack;
      int r = 0;
      while (rp_s[r + 1] <= jb) ++r;
      float acc[8];
#pragma unroll
      for (int c = 0; c < 8; ++c) acc[c] = 0.f;
      // preload first batch's descriptors (laneset-broadcast, as R14)
      int h = jb >> 1;
      int4 q0 = ep4[h + 0];
      int4 q1 = ep4[h + 1];
      int4 q2 = ep4[h + 2];
      int4 q3 = ep4[h + 3];
      for (int j = jb; j < je; j += 8) {
        if (rp_s[r + 1] <= j) {
          float* bp = &xm[r * 128 + fl * 8];
#pragma unroll
          for (int c = 0; c < 8; ++c) { atomicAdd(bp + c, acc[c]); acc[c] = 0.f; }
          do { ++r; } while (rp_s[r + 1] <= j);
        }
        // select this batch's (src, w) for this lane's grp, then gather h8
        const int   s0 = grp ? q0.z : q0.x;
        const int   s1 = grp ? q1.z : q1.x;
        const int   s2 = grp ? q2.z : q2.x;
        const int   s3 = grp ? q3.z : q3.x;
        const float w0 = __int_as_float(grp ? q0.w : q0.y);
        const float w1 = __int_as_float(grp ? q1.w : q1.y);
        const float w2 = __int_as_float(grp ? q2.w : q2.y);
        const float w3 = __int_as_float(grp ? q3.w : q3.y);
        const h8 u0 = *(const h8*)&xinh[(size_t)s0 * 128 + fl * 8];
        const h8 u1 = *(const h8*)&xinh[(size_t)s1 * 128 + fl * 8];
        const h8 u2 = *(const h8*)&xinh[(size_t)s2 * 128 + fl * 8];
        const h8 u3 = *(const h8*)&xinh[(size_t)s3 * 128 + fl * 8];
        // prefetch NEXT batch's descriptors (clamped, branch-free)
        const int jn = (j + 8 < je) ? (j + 8) : j;
        const int hn = jn >> 1;
        q0 = ep4[hn + 0];
        q1 = ep4[hn + 1];
        q2 = ep4[hn + 2];
        q3 = ep4[hn + 3];
        fma8(acc, u0, w0);
        fma8(acc, u1, w1);
        fma8(acc, u2, w2);
        fma8(acc, u3, w3);
      }
      float* bp = &xm[r * 128 + fl * 8];
#pragma unroll
      for (int c = 0; c < 8; ++c) atomicAdd(bp + c, acc[c]);
    }
  }
  __syncthreads();

  // ---- stage 2: in-place finalize (1+eps)*x + agg/deg (natural layout) ----
  {
#pragma unroll
    for (int q = 0; q < 4; ++q) {
      const int task = t + q * 256;
      const int r = task >> 5;
      const int fg = task & 31;
      const int f0 = fg * 4;
      const int node = nb + r;
      float4 v = make_float4(0.f, 0.f, 0.f, 0.f);
      if (node < n) {
        const int d = cnt[node];
        const float rdeg = 1.0f / (float)(d > 1 ? d : 1);
        const float4 xv = *(const float4*)&xin[(size_t)node * 128 + f0];
        const float4 m = *(const float4*)&xm[r * 128 + f0];
        v.x = epsv * xv.x + m.x * rdeg;
        v.y = epsv * xv.y + m.y * rdeg;
        v.z = epsv * xv.z + m.z * rdeg;
        v.w = epsv * xv.w + m.w * rdeg;
      }
      *(float4*)&xm[r * 128 + f0] = v;   // each (r,f0) owned by one thread
    }
  }
  __syncthreads();

  // ---- stage 3: GEMM, thread tile = 4 rows x 4 features ----
  {
    const int fg = t & 31;
    const int rg = t >> 5;
    const int f0 = fg * 4;
    const int r0 = rg * 4;
    float4 acc[4];
#pragma unroll
    for (int r = 0; r < 4; ++r) acc[r] = make_float4(0.f, 0.f, 0.f, 0.f);
    for (int k = 0; k < 128; k += 4) {
      const float4 w0 = *(const float4*)&Wt[(k + 0) * 128 + f0];
      const float4 w1 = *(const float4*)&Wt[(k + 1) * 128 + f0];
      const float4 w2 = *(const float4*)&Wt[(k + 2) * 128 + f0];
      const float4 w3 = *(const float4*)&Wt[(k + 3) * 128 + f0];
#pragma unroll
      for (int r = 0; r < 4; ++r) {
        const float4 xv = *(const float4*)&xm[(r0 + r) * 128 + k];
        acc[r].x += xv.x * w0.x + xv.y * w1.x + xv.z * w2.x + xv.w * w3.x;
        acc[r].y += xv.x * w0.y + xv.y * w1.y + xv.z * w2.y + xv.w * w3.y;
        acc[r].z += xv.x * w0.z + xv.y * w1.z + xv.z * w2.z + xv.w * w3.z;
        acc[r].w += xv.x * w0.w + xv.y * w1.w + xv.z * w2.w + xv.w * w3.w;
      }
    }
    const float4 bv = *(const float4*)&bias[f0];
#pragma unroll
    for (int r = 0; r < 4; ++r) {
      const int node = nb + r0 + r;
      if (node < n) {
        float4 v;
        v.x = acc[r].x + bv.x;
        v.y = acc[r].y + bv.y;
        v.z = acc[r].z + bv.z;
        v.w = acc[r].w + bv.w;
        if (dorelu) {
          v.x = fmaxf(v.x, 0.f); v.y = fmaxf(v.y, 0.f);
          v.z = fmaxf(v.z, 0.f); v.w = fmaxf(v.w, 0.f);
        }
        if (zerorow0 && node == 0) { v.x = 0.f; v.y = 0.f; v.z = 0.f; v.w = 0.f; }
        *(h4*)&xouth[(size_t)node * 128 + f0] = f4h(v);
        if (writef32) *(float4*)&xout[(size_t)node * 128 + f0] = v;
      }
    }
  }
}

// Final MLP: 8 elems per 256-thread block (512 blocks); x2 gathers in fp16.
__launch_bounds__(256, 4)
__global__ void final_kernel(const __half* __restrict__ x2h, const int* __restrict__ indices,
                             const float* __restrict__ Wc1t, const float* __restrict__ bc1,
                             const float* __restrict__ Wc2t, const float* __restrict__ bc2,
                             const float* __restrict__ Wc3, const float* __restrict__ bc3,
                             float* __restrict__ out) {
  __shared__ float ysm[FIN_EPB * 384];
  __shared__ float h1s[FIN_EPB * 128];
  __shared__ float h2s[FIN_EPB * 64];
  __shared__ int ind_s[FIN_EPB * 23];
  __shared__ float ccs[FIN_EPB];
  const int t = threadIdx.x;
  const int b0 = blockIdx.x * FIN_EPB;

  if (t < FIN_EPB * 23) ind_s[t] = indices[(size_t)b0 * 23 + t];
  __syncthreads();
  if (t < FIN_EPB) {
    int cc = 0;
#pragma unroll
    for (int j = 0; j < 20; ++j) cc += (ind_s[t * 23 + 3 + j] > 0) ? 1 : 0;
    ccs[t] = 1.0f / (float)(cc > 0 ? cc : 1);
  }
  __syncthreads();

  // ---- phase A ----
  {
#pragma unroll
    for (int q = 0; q < 2; ++q) {
      const int s = t + q * 256;
      const int e = s >> 6;
      const int hf = (s >> 5) & 1;
      const int fg = s & 31;
      const int idx = ind_s[e * 23 + hf];
      const h4 u = *(const h4*)&x2h[(size_t)idx * 128 + fg * 4];
      *(float4*)&ysm[e * 384 + hf * 128 + fg * 4] = h4f(u);
    }
    const int e = t >> 5;
    const int fg = t & 31;
    float4 acc = make_float4(0.f, 0.f, 0.f, 0.f);
#pragma unroll
    for (int j = 0; j < 20; ++j) {
      const int cj = ind_s[e * 23 + 3 + j];
      const h4 u = *(const h4*)&x2h[(size_t)cj * 128 + fg * 4];
      const float4 a = h4f(u);
      acc.x += a.x; acc.y += a.y; acc.z += a.z; acc.w += a.w;
    }
    const float sc = ccs[e];
    acc.x *= sc; acc.y *= sc; acc.z *= sc; acc.w *= sc;
    *(float4*)&ysm[e * 384 + 256 + fg * 4] = acc;
  }
  __syncthreads();

  // ---- phase B: layer 1 (384 -> 128), 4 elems per thread ----
  {
    const int f1 = t & 127;
    const int eh = t >> 7;
    float acc[4];
    const float b = bc1[f1];
#pragma unroll
    for (int i = 0; i < 4; ++i) acc[i] = b;
    for (int k = 0; k < 384; k += 4) {
      const float wv0 = Wc1t[(k + 0) * 128 + f1];
      const float wv1 = Wc1t[(k + 1) * 128 + f1];
      const float wv2 = Wc1t[(k + 2) * 128 + f1];
      const float wv3 = Wc1t[(k + 3) * 128 + f1];
#pragma unroll
      for (int i = 0; i < 4; ++i) {
        const float4 yv = *(const float4*)&ysm[(eh * 4 + i) * 384 + k];
        acc[i] += yv.x * wv0 + yv.y * wv1 + yv.z * wv2 + yv.w * wv3;
      }
    }
#pragma unroll
    for (int i = 0; i < 4; ++i)
      h1s[(eh * 4 + i) * 128 + f1] = fmaxf(acc[i], 0.f);
  }
  __syncthreads();

  // ---- phase C: layer 2 (128 -> 64), 2 elems per thread ----
  {
    const int f2 = t & 63;
    const int eg = t >> 6;
    float acc[2];
    const float b = bc2[f2];
#pragma unroll
    for (int i = 0; i < 2; ++i) acc[i] = b;
    for (int k = 0; k < 128; k += 4) {
      const float wv0 = Wc2t[(k + 0) * 64 + f2];
      const float wv1 = Wc2t[(k + 1) * 64 + f2];
      const float wv2 = Wc2t[(k + 2) * 64 + f2];
      const float wv3 = Wc2t[(k + 3) * 64 + f2];
#pragma unroll
      for (int i = 0; i < 2; ++i) {
        const float4 hv = *(const float4*)&h1s[(eg * 2 + i) * 128 + k];
        acc[i] += hv.x * wv0 + hv.y * wv1 + hv.z * wv2 + hv.w * wv3;
      }
    }
#pragma unroll
    for (int i = 0; i < 2; ++i)
      h2s[(eg * 2 + i) * 64 + f2] = fmaxf(acc[i], 0.f);
  }
  __syncthreads();

  // ---- phase D: layer 3 (64 -> 1), 32 lanes per element ----
  {
    const int e = t >> 5;
    const int l = t & 31;
    float p = h2s[e * 64 + l] * Wc3[l] + h2s[e * 64 + l + 32] * Wc3[l + 32];
#pragma unroll
    for (int o = 16; o > 0; o >>= 1) p += __shfl_down(p, o, 32);
    if (l == 0) out[b0 + e] = p + bc3[0];
  }
}

extern "C" void kernel_launch(void* const* d_in, const int* in_sizes, int n_in,
                              void* d_out, int out_size, void* d_ws, size_t ws_size,
                              hipStream_t stream) {
  const int* indices = (const int*)d_in[0];
  const int* src = (const int*)d_in[1];
  const int* dst = (const int*)d_in[2];
  const float* w = (const float*)d_in[3];
  const float* ndata = (const float*)d_in[4];
  const float* W1 = (const float*)d_in[5];
  const float* b1 = (const float*)d_in[6];
  const float* W2 = (const float*)d_in[7];
  const float* b2 = (const float*)d_in[8];
  const float* eps = (const float*)d_in[9];
  const float* Wc1 = (const float*)d_in[10];
  const float* bc1 = (const float*)d_in[11];
  const float* Wc2 = (const float*)d_in[12];
  const float* bc2 = (const float*)d_in[13];
  const float* Wc3 = (const float*)d_in[14];
  const float* bc3 = (const float*)d_in[15];
  float* out = (float*)d_out;

  const int E = in_sizes[1];
  const int N = in_sizes[4] / 128;
  const int B = in_sizes[0] / 23;

  char* ws = (char*)d_ws;
  size_t off = 0;
  auto alloc = [&](size_t bytes) -> char* {
    char* p = ws + off;
    off = (off + bytes + 255) & ~(size_t)255;
    return p;
  };
  const size_t Epad = (size_t)E + 8 * (size_t)N;   // worst-case padded edge count
  int* cnt = (int*)alloc((size_t)N * 4);
  int* prow = (int*)alloc((size_t)(N + 1) * 4);
  int* rank = (int*)alloc((size_t)E * 4);
  int* bsum = (int*)alloc(256 * 4);
  int2* epack = (int2*)alloc(Epad * 8);
  float* x1 = (float*)alloc((size_t)N * 128 * 4);          // f32 x1 (conv2 self term)
  __half* xh0 = (__half*)alloc((size_t)N * 128 * 2);       // fp16 ndata; reused as x2h
  __half* x1h = (__half*)alloc((size_t)N * 128 * 2);       // fp16 x1 (conv2 gathers)
  float* Wt1 = (float*)alloc(16384 * 4);
  float* Wt2 = (float*)alloc(16384 * 4);
  float* Wc1t = (float*)alloc(49152 * 4);
  float* Wc2t = (float*)alloc(8192 * 4);
  __half* x2h = xh0;   // xh0 dead after conv1; conv2 writes x2 (fp16) here

  const int ncast = (N * 128 + 7) / 8;                     // 1.6M cast threads
  int ninit = (N > 90112) ? N : 90112;
  if (ncast > ninit) ninit = ncast;
  init_kernel<<<(ninit + 255) / 256, 256, 0, stream>>>(W1, W2, Wc1, Wc2, ndata, xh0,
                                                       Wt1, Wt2, Wc1t, Wc2t, cnt, N);
  const int Eq = (E + 3) / 4;
  hist_kernel<<<(Eq + 255) / 256, 256, 0, stream>>>(dst, cnt, rank, E);
  const int nchunk = (N + 2047) / 2048;
  scan1_kernel<<<nchunk, 256, 0, stream>>>(cnt, prow, bsum, N);
  scan2_kernel<<<1, 64, 0, stream>>>(bsum, nchunk);
  const int nsc = (Eq > N) ? Eq : N;
  scatter_kernel<<<(nsc + 255) / 256, 256, 0, stream>>>(src, dst, w, prow, bsum, rank, cnt, epack, E, N);

  const int nconv = (N + CONV_NPB - 1) / CONV_NPB;
  // conv1: gathers fp16(ndata), self term f32 ndata; writes x1 (f32) + x1h (fp16)
  conv_kernel<<<nconv, 256, 0, stream>>>(ndata, xh0, x1, x1h, prow, bsum, cnt, epack,
                                         Wt1, b1, eps, 0, 1, 0, 1, N, nchunk);
  // conv2: gathers x1h, self term f32 x1; writes x2h (fp16 only, into xh0 buffer)
  conv_kernel<<<nconv, 256, 0, stream>>>(x1, x1h, nullptr, x2h, prow, bsum, cnt, epack,
                                         Wt2, b2, eps, 1, 0, 1, 0, N, nchunk);

  final_kernel<<<B / FIN_EPB, 256, 0, stream>>>(x2h, indices, Wc1t, bc1, Wc2t, bc2, Wc3, bc3, out);
}